// Round 4
// baseline (259.698 us; speedup 1.0000x reference)
//
#include <hip/hip_runtime.h>

// 8 stacked 3x3 same-pad convs on independent 3x3 images == one affine map
// out = A*x + c (A: 9x9, c: 9). compose_affine builds it in d_ws each call;
// apply_affine streams 4M rows through it.
//
// R8: global_load_lds staging. R5 (pipelining), R7 (LDS-op reduction) both
// null -> the wave schedule is fully hidden at 16 waves/CU; apply is pinned
// at ~4 TB/s by the memory path. Single-lever change vs R7: input staging
// switches from nt-load->VGPR->ds_write to the direct global->LDS DMA
// (__builtin_amdgcn_global_load_lds, width 16, aux=0 default caching).
// Its HW dest semantics (wave-uniform base + lane*16) exactly produce
// R7's linear layout t4[L + j*64]. Compute path, b128 transpose, nt
// stores all byte-identical to R7.

typedef float v4f __attribute__((ext_vector_type(4)));
typedef __attribute__((address_space(1))) const void gconst_t;
typedef __attribute__((address_space(3))) void lds_t;

// ---------------- Kernel 1: compose the affine map --------------------------
__global__ void compose_affine(const float* __restrict__ w,   // [8,3,3] flat
                               const float* __restrict__ b,   // [8]
                               float* __restrict__ aff)       // [90]: A(81), c(9)
{
    __shared__ float W[72];
    __shared__ float B[8];
    __shared__ float A[2][81];
    __shared__ float C[2][9];
    const int t = threadIdx.x;

    if (t < 72) W[t] = w[t];
    if (t >= 72 && t < 80) B[t - 72] = b[t - 72];
    if (t < 81) A[0][t] = (t / 9 == t % 9) ? 1.0f : 0.0f;
    if (t < 9)  C[0][t] = 0.0f;
    __syncthreads();

    int cur = 0;
    for (int d = 0; d < 8; ++d) {
        if (t < 81) {
            const int i = t / 9, j = t % 9;
            const int r = i / 3, cc = i % 3;
            float acc = 0.0f;
            float accc = (j == 0) ? B[d] : 0.0f;
            #pragma unroll
            for (int k = 0; k < 9; ++k) {
                const int rr = k / 3, kc = k % 3;
                const int dr = rr - r + 1, dc = kc - cc + 1;
                float m = 0.0f;
                if (dr >= 0 && dr < 3 && dc >= 0 && dc < 3)
                    m = W[d * 9 + dr * 3 + dc];
                acc = fmaf(m, A[cur][k * 9 + j], acc);
                if (j == 0) accc = fmaf(m, C[cur][k], accc);
            }
            A[1 - cur][t] = acc;
            if (j == 0) C[1 - cur][i] = accc;
        }
        __syncthreads();
        cur = 1 - cur;
    }
    if (t < 81) aff[t] = A[cur][t];
    if (t < 9)  aff[81 + t] = C[cur][t];
}

// ---------------- Kernel 2: wave-autonomous b128-transpose affine apply -----
// Tile: 256 rows = 576 v4f = 2304 floats. Stage-in via global_load_lds:
// op j writes LDS quads [j*64 + L] (lane L at uniform base + L*16) from
// global quads base + j*64 + L -- linear, coalesced, 1 KiB per op.
// Lane L computes rows [4L, 4L+4) from LDS v4f [9L, 9L+9)
// (quad-stride 9 == 1 mod 8 -> conflict-free b128).
__global__ __launch_bounds__(64) void apply_affine(
    const v4f* __restrict__ in4,
    const float* __restrict__ aff,
    v4f* __restrict__ out4,
    long long n_f4)
{
    __shared__ float tile[2304];   // 9216 B
    v4f* __restrict__ t4 = (v4f*)tile;
    const int L = threadIdx.x;
    const long long base = (long long)blockIdx.x * 576;

    // ---- stage in: 9 x global_load_lds_dwordx4, direct to LDS ----
    if (base + 576 <= n_f4) {
        #pragma unroll
        for (int j = 0; j < 9; ++j)
            __builtin_amdgcn_global_load_lds(
                (gconst_t*)(in4 + base + L + (long long)j * 64),
                (lds_t*)(t4 + j * 64),
                16, 0, 0);
        asm volatile("s_waitcnt vmcnt(0)" ::: "memory");
        __builtin_amdgcn_sched_barrier(0);
    } else {
        // generic tail path (never taken at N=4M: 15625*576 == 9M exactly)
        #pragma unroll
        for (int j = 0; j < 9; ++j) {
            const long long g = base + L + (long long)j * 64;
            t4[L + j * 64] = (g < n_f4) ? in4[g] : (v4f)0.0f;
        }
        __syncthreads();
    }

    // ---- gather 4 whole rows into registers: 9 x ds_read_b128 ----
    v4f d[9];
    #pragma unroll
    for (int q = 0; q < 9; ++q) d[q] = t4[9 * L + q];

    // ---- compute 4 rows, fully register-resident, static indexing ----
    #pragma unroll
    for (int rr = 0; rr < 4; ++rr) {
        float xv[9];
        #pragma unroll
        for (int k = 0; k < 9; ++k) {
            const int fi = 9 * rr + k;             // static
            xv[k] = d[fi >> 2][fi & 3];
        }
        float y[9];
        #pragma unroll
        for (int i = 0; i < 9; ++i) y[i] = aff[81 + i];
        #pragma unroll
        for (int k = 0; k < 9; ++k) {
            #pragma unroll
            for (int i = 0; i < 9; ++i)
                y[i] = fmaf(aff[i * 9 + k], xv[k], y[i]);   // aff -> SGPR (uniform)
        }
        #pragma unroll
        for (int k = 0; k < 9; ++k) {
            const int fi = 9 * rr + k;             // static
            d[fi >> 2][fi & 3] = y[k];
        }
    }

    // ---- write back: 9 x ds_write_b128 ----
    #pragma unroll
    for (int q = 0; q < 9; ++q) t4[9 * L + q] = d[q];
    __syncthreads();   // single-wave wg: compiles to waitcnt only

    // ---- stage out: 9 coalesced nt float4 stores ----
    v4f r[9];
    #pragma unroll
    for (int j = 0; j < 9; ++j) r[j] = t4[L + j * 64];
    if (base + 576 <= n_f4) {
        #pragma unroll
        for (int j = 0; j < 9; ++j)
            __builtin_nontemporal_store(r[j], out4 + base + L + (long long)j * 64);
    } else {
        #pragma unroll
        for (int j = 0; j < 9; ++j) {
            const long long g = base + L + (long long)j * 64;
            if (g < n_f4) __builtin_nontemporal_store(r[j], out4 + g);
        }
    }
}

extern "C" void kernel_launch(void* const* d_in, const int* in_sizes, int n_in,
                              void* d_out, int out_size, void* d_ws, size_t ws_size,
                              hipStream_t stream) {
    const float* x = (const float*)d_in[0];   // [N,9] fp32
    const float* w = (const float*)d_in[1];   // [8,1,1,3,3] fp32
    const float* b = (const float*)d_in[2];   // [8] fp32
    float* out = (float*)d_out;
    float* aff = (float*)d_ws;                // 90 floats

    const long long n_elems = (long long)in_sizes[0];   // 36,000,000
    const long long n_f4    = n_elems / 4;              // 9,000,000
    const long long tiles   = (n_f4 + 575) / 576;       // 15,625 (exact)

    compose_affine<<<1, 128, 0, stream>>>(w, b, aff);
    apply_affine<<<dim3((unsigned)tiles), dim3(64), 0, stream>>>(
        (const v4f*)x, aff, (v4f*)out, n_f4);
}

// Round 5
// 257.657 us; speedup vs baseline: 1.0079x; 1.0079x over previous
//
#include <hip/hip_runtime.h>

// 8 stacked 3x3 same-pad convs on independent 3x3 images == one affine map
// out = A*x + c (A: 9x9, c: 9). compose_affine builds it in d_ws each call;
// apply_affine streams 4M rows through it.
//
// R9: cache-policy + wg-granularity ablation on the proven R7 structure.
// R8's direct counters: apply = 88.5us, VALU 6%, LDS ~12%, HBM 30%,
// conflicts 0 -> nothing in the CU is busy; the pattern's memory rate
// (~4 TB/s) is the wall. Two untested levers, both low-risk:
//  (a) drop ALL nontemporal hints. R8 showed default loads get ~50% L3
//      hits (FETCH 70MB < 144MB input); nt evict-first forfeits that and
//      forces eager HBM write drain. Output (144MB) fits in L3 -> default
//      stores can park in L3 and drain off the critical path.
//  (b) 4-wave barrier-free wgs: 256 threads, each wave an independent
//      tile + private 9216B LDS slice, zero __syncthreads. Removes
//      15,625 single-wave wg slot-churn events and lockstep coupling.
//      LDS/CU usage unchanged (147KB) -> occupancy cannot regress.
// Everything else (VGPR staging, all-b128 conflict-free transpose,
// register-resident compute with static v4f indexing) identical to R7.

typedef float v4f __attribute__((ext_vector_type(4)));

// ---------------- Kernel 1: compose the affine map --------------------------
__global__ void compose_affine(const float* __restrict__ w,   // [8,3,3] flat
                               const float* __restrict__ b,   // [8]
                               float* __restrict__ aff)       // [90]: A(81), c(9)
{
    __shared__ float W[72];
    __shared__ float B[8];
    __shared__ float A[2][81];
    __shared__ float C[2][9];
    const int t = threadIdx.x;

    if (t < 72) W[t] = w[t];
    if (t >= 72 && t < 80) B[t - 72] = b[t - 72];
    if (t < 81) A[0][t] = (t / 9 == t % 9) ? 1.0f : 0.0f;
    if (t < 9)  C[0][t] = 0.0f;
    __syncthreads();

    int cur = 0;
    for (int d = 0; d < 8; ++d) {
        if (t < 81) {
            const int i = t / 9, j = t % 9;
            const int r = i / 3, cc = i % 3;
            float acc = 0.0f;
            float accc = (j == 0) ? B[d] : 0.0f;
            #pragma unroll
            for (int k = 0; k < 9; ++k) {
                const int rr = k / 3, kc = k % 3;
                const int dr = rr - r + 1, dc = kc - cc + 1;
                float m = 0.0f;
                if (dr >= 0 && dr < 3 && dc >= 0 && dc < 3)
                    m = W[d * 9 + dr * 3 + dc];
                acc = fmaf(m, A[cur][k * 9 + j], acc);
                if (j == 0) accc = fmaf(m, C[cur][k], accc);
            }
            A[1 - cur][t] = acc;
            if (j == 0) C[1 - cur][i] = accc;
        }
        __syncthreads();
        cur = 1 - cur;
    }
    if (t < 81) aff[t] = A[cur][t];
    if (t < 9)  aff[81 + t] = C[cur][t];
}

// ---------------- Kernel 2: barrier-free 4-wave affine apply ----------------
// Wave w of block b owns tile t = 4b + w: 256 rows = 576 v4f, staged in a
// private LDS slice. Lane L stages v4f (L + 64j), j=0..8 (coalesced,
// quad-stride 1); computes rows [4L, 4L+4) from LDS v4f [9L, 9L+9)
// (quad-stride 9 == 1 mod 8 -> conflict-free b128). No __syncthreads:
// waves never share LDS; intra-wave ds_write->ds_read ordering comes from
// program order + compiler lgkmcnt waits.
__global__ __launch_bounds__(256) void apply_affine(
    const v4f* __restrict__ in4,
    const float* __restrict__ aff,
    v4f* __restrict__ out4,
    long long n_f4,
    long long n_tiles)
{
    __shared__ float tile[4 * 2304];   // 36,864 B = 4 private 9216B slices
    const int w = threadIdx.x >> 6;
    const int L = threadIdx.x & 63;
    v4f* __restrict__ t4 = (v4f*)(tile + w * 2304);

    const long long t = 4LL * blockIdx.x + w;
    if (t >= n_tiles) return;
    const long long base = t * 576;

    // ---- stage in: 9 coalesced float4 loads (default caching) ----
    v4f r[9];
    if (base + 576 <= n_f4) {
        #pragma unroll
        for (int j = 0; j < 9; ++j)
            r[j] = in4[base + L + (long long)j * 64];
    } else {
        #pragma unroll
        for (int j = 0; j < 9; ++j) {
            const long long g = base + L + (long long)j * 64;
            r[j] = (g < n_f4) ? in4[g] : (v4f)0.0f;
        }
    }
    #pragma unroll
    for (int j = 0; j < 9; ++j) t4[L + j * 64] = r[j];
    __builtin_amdgcn_wave_barrier();   // scheduling fence (free)

    // ---- gather 4 whole rows into registers: 9 x ds_read_b128 ----
    v4f d[9];
    #pragma unroll
    for (int q = 0; q < 9; ++q) d[q] = t4[9 * L + q];

    // ---- compute 4 rows, fully register-resident, static indexing ----
    #pragma unroll
    for (int rr = 0; rr < 4; ++rr) {
        float xv[9];
        #pragma unroll
        for (int k = 0; k < 9; ++k) {
            const int fi = 9 * rr + k;             // static
            xv[k] = d[fi >> 2][fi & 3];
        }
        float y[9];
        #pragma unroll
        for (int i = 0; i < 9; ++i) y[i] = aff[81 + i];
        #pragma unroll
        for (int k = 0; k < 9; ++k) {
            #pragma unroll
            for (int i = 0; i < 9; ++i)
                y[i] = fmaf(aff[i * 9 + k], xv[k], y[i]);   // aff -> SGPR (uniform)
        }
        #pragma unroll
        for (int k = 0; k < 9; ++k) {
            const int fi = 9 * rr + k;             // static
            d[fi >> 2][fi & 3] = y[k];
        }
    }

    // ---- write back: 9 x ds_write_b128 ----
    #pragma unroll
    for (int q = 0; q < 9; ++q) t4[9 * L + q] = d[q];
    __builtin_amdgcn_wave_barrier();

    // ---- stage out: 9 coalesced float4 stores (default caching) ----
    #pragma unroll
    for (int j = 0; j < 9; ++j) r[j] = t4[L + j * 64];
    if (base + 576 <= n_f4) {
        #pragma unroll
        for (int j = 0; j < 9; ++j)
            out4[base + L + (long long)j * 64] = r[j];
    } else {
        #pragma unroll
        for (int j = 0; j < 9; ++j) {
            const long long g = base + L + (long long)j * 64;
            if (g < n_f4) out4[g] = r[j];
        }
    }
}

extern "C" void kernel_launch(void* const* d_in, const int* in_sizes, int n_in,
                              void* d_out, int out_size, void* d_ws, size_t ws_size,
                              hipStream_t stream) {
    const float* x = (const float*)d_in[0];   // [N,9] fp32
    const float* w = (const float*)d_in[1];   // [8,1,1,3,3] fp32
    const float* b = (const float*)d_in[2];   // [8] fp32
    float* out = (float*)d_out;
    float* aff = (float*)d_ws;                // 90 floats

    const long long n_elems = (long long)in_sizes[0];   // 36,000,000
    const long long n_f4    = n_elems / 4;              // 9,000,000
    const long long tiles   = (n_f4 + 575) / 576;       // 15,625 (exact)
    const long long blocks  = (tiles + 3) / 4;          // 3,907

    compose_affine<<<1, 128, 0, stream>>>(w, b, aff);
    apply_affine<<<dim3((unsigned)blocks), dim3(256), 0, stream>>>(
        (const v4f*)x, aff, (v4f*)out, n_f4, tiles);
}

// Round 6
// 250.628 us; speedup vs baseline: 1.0362x; 1.0280x over previous
//
#include <hip/hip_runtime.h>

// 8 stacked 3x3 same-pad convs on independent 3x3 images == one affine map
// out = A*x + c (A: 9x9, c: 9). compose_affine builds it in d_ws each call;
// apply_affine streams 4M rows through it.
//
// R10: cache-policy 2x2, final cell: nt LOADS + DEFAULT stores.
// Evidence: {nt,nt}=70-73us, {dflt,nt}=88.5, {dflt,dflt}=85.8 -> default
// loads are the slow component (L1/L2 alloc churn on a 144MB stream);
// nt loads fast. Only demonstrated-fast write policy on this machine is
// default (fills: 576MB write-only @ 6.5 TB/s, plain stores); nt stores
// plausibly drain eagerly at ~2.2 TB/s effective, which would explain the
// 4.1 TB/s plateau of {nt,nt}. Structure byte-identical to R7 (best
// timed, all-b128 conflict-free transpose, register-resident compute):
// only the 9 output stores lose their nontemporal hint.

typedef float v4f __attribute__((ext_vector_type(4)));

// ---------------- Kernel 1: compose the affine map --------------------------
__global__ void compose_affine(const float* __restrict__ w,   // [8,3,3] flat
                               const float* __restrict__ b,   // [8]
                               float* __restrict__ aff)       // [90]: A(81), c(9)
{
    __shared__ float W[72];
    __shared__ float B[8];
    __shared__ float A[2][81];
    __shared__ float C[2][9];
    const int t = threadIdx.x;

    if (t < 72) W[t] = w[t];
    if (t >= 72 && t < 80) B[t - 72] = b[t - 72];
    if (t < 81) A[0][t] = (t / 9 == t % 9) ? 1.0f : 0.0f;
    if (t < 9)  C[0][t] = 0.0f;
    __syncthreads();

    int cur = 0;
    for (int d = 0; d < 8; ++d) {
        if (t < 81) {
            const int i = t / 9, j = t % 9;
            const int r = i / 3, cc = i % 3;
            float acc = 0.0f;
            float accc = (j == 0) ? B[d] : 0.0f;
            #pragma unroll
            for (int k = 0; k < 9; ++k) {
                const int rr = k / 3, kc = k % 3;
                const int dr = rr - r + 1, dc = kc - cc + 1;
                float m = 0.0f;
                if (dr >= 0 && dr < 3 && dc >= 0 && dc < 3)
                    m = W[d * 9 + dr * 3 + dc];
                acc = fmaf(m, A[cur][k * 9 + j], acc);
                if (j == 0) accc = fmaf(m, C[cur][k], accc);
            }
            A[1 - cur][t] = acc;
            if (j == 0) C[1 - cur][i] = accc;
        }
        __syncthreads();
        cur = 1 - cur;
    }
    if (t < 81) aff[t] = A[cur][t];
    if (t < 9)  aff[81 + t] = C[cur][t];
}

// ---------------- Kernel 2: wave-autonomous b128-transpose affine apply -----
// Tile: 256 rows = 576 v4f = 2304 floats. Lane L stages v4f (L + 64j),
// j=0..8 (coalesced, LDS quad-stride 1); computes rows [4L, 4L+4) from
// LDS v4f [9L, 9L+9) (quad-stride 9 == 1 mod 8 -> conflict-free b128).
__global__ __launch_bounds__(64) void apply_affine(
    const v4f* __restrict__ in4,
    const float* __restrict__ aff,
    v4f* __restrict__ out4,
    long long n_f4)
{
    __shared__ float tile[2304];   // 9216 B
    v4f* __restrict__ t4 = (v4f*)tile;
    const int L = threadIdx.x;
    const long long base = (long long)blockIdx.x * 576;

    // ---- stage in: 9 coalesced nt float4 loads, all in flight together ----
    v4f r[9];
    if (base + 576 <= n_f4) {
        #pragma unroll
        for (int j = 0; j < 9; ++j)
            r[j] = __builtin_nontemporal_load(in4 + base + L + (long long)j * 64);
    } else {
        #pragma unroll
        for (int j = 0; j < 9; ++j) {
            const long long g = base + L + (long long)j * 64;
            r[j] = (g < n_f4) ? __builtin_nontemporal_load(in4 + g) : (v4f)0.0f;
        }
    }
    #pragma unroll
    for (int j = 0; j < 9; ++j) t4[L + j * 64] = r[j];
    __syncthreads();   // single-wave wg: just the lgkm/vm drain

    // ---- gather 4 whole rows into registers: 9 x ds_read_b128 ----
    v4f d[9];
    #pragma unroll
    for (int q = 0; q < 9; ++q) d[q] = t4[9 * L + q];

    // ---- compute 4 rows, fully register-resident, static indexing ----
    #pragma unroll
    for (int rr = 0; rr < 4; ++rr) {
        float xv[9];
        #pragma unroll
        for (int k = 0; k < 9; ++k) {
            const int fi = 9 * rr + k;             // static
            xv[k] = d[fi >> 2][fi & 3];
        }
        float y[9];
        #pragma unroll
        for (int i = 0; i < 9; ++i) y[i] = aff[81 + i];
        #pragma unroll
        for (int k = 0; k < 9; ++k) {
            #pragma unroll
            for (int i = 0; i < 9; ++i)
                y[i] = fmaf(aff[i * 9 + k], xv[k], y[i]);   // aff -> SGPR (uniform)
        }
        #pragma unroll
        for (int k = 0; k < 9; ++k) {
            const int fi = 9 * rr + k;             // static
            d[fi >> 2][fi & 3] = y[k];
        }
    }

    // ---- write back: 9 x ds_write_b128 ----
    #pragma unroll
    for (int q = 0; q < 9; ++q) t4[9 * L + q] = d[q];
    __syncthreads();

    // ---- stage out: 9 coalesced DEFAULT float4 stores (L2 write-combine) ---
    #pragma unroll
    for (int j = 0; j < 9; ++j) r[j] = t4[L + j * 64];
    if (base + 576 <= n_f4) {
        #pragma unroll
        for (int j = 0; j < 9; ++j)
            out4[base + L + (long long)j * 64] = r[j];
    } else {
        #pragma unroll
        for (int j = 0; j < 9; ++j) {
            const long long g = base + L + (long long)j * 64;
            if (g < n_f4) out4[g] = r[j];
        }
    }
}

extern "C" void kernel_launch(void* const* d_in, const int* in_sizes, int n_in,
                              void* d_out, int out_size, void* d_ws, size_t ws_size,
                              hipStream_t stream) {
    const float* x = (const float*)d_in[0];   // [N,9] fp32
    const float* w = (const float*)d_in[1];   // [8,1,1,3,3] fp32
    const float* b = (const float*)d_in[2];   // [8] fp32
    float* out = (float*)d_out;
    float* aff = (float*)d_ws;                // 90 floats

    const long long n_elems = (long long)in_sizes[0];   // 36,000,000
    const long long n_f4    = n_elems / 4;              // 9,000,000
    const long long tiles   = (n_f4 + 575) / 576;       // 15,625 (exact)

    compose_affine<<<1, 128, 0, stream>>>(w, b, aff);
    apply_affine<<<dim3((unsigned)tiles), dim3(64), 0, stream>>>(
        (const v4f*)x, aff, (v4f*)out, n_f4);
}

// Round 7
// 245.425 us; speedup vs baseline: 1.0582x; 1.0212x over previous
//
#include <hip/hip_runtime.h>

// 8 stacked 3x3 same-pad convs on independent 3x3 images == one affine map
// out = A*x + c (A: 9x9, c: 9). compose_affine builds it in d_ws each call;
// apply_affine streams 4M rows through it.
//
// FINAL (restores R4, the session's best-measured variant: 248.2/246.4 us).
// Exoneration ledger from R5-R10 (all within-harness measurements):
//  - R5  persistent + 2-deep pipeline: null (TLP already hides latency)
//  - R6  no-LDS 144B-stride global:    -25% (TA request-rate limited)
//  - R7  all-b128 LDS transpose:       null (LDS pipe ~12%, not critical)
//  - R8  global_load_lds DMA staging:  -5% (vmcnt(0) serialization)
//  - R9  4-wave barrier-free wgs:      null structure; default loads -15us
//  - R10 nt loads + default stores:    null (store policy neutral)
// Timed region decomposes as 2x87us harness fills + ~3us compose + ~70us
// apply (~4.1 TB/s). Every internal counter idle (VALU 6.5%, LDS conflicts
// 0, FETCH/WRITE = ideal bytes); no tested lever moves apply. This is the
// pattern's measured ceiling on this harness.

typedef float v4f __attribute__((ext_vector_type(4)));

// ---------------- Kernel 1: compose the affine map --------------------------
__global__ void compose_affine(const float* __restrict__ w,   // [8,3,3] flat
                               const float* __restrict__ b,   // [8]
                               float* __restrict__ aff)       // [90]: A(81), c(9)
{
    __shared__ float W[72];
    __shared__ float B[8];
    __shared__ float A[2][81];
    __shared__ float C[2][9];
    const int t = threadIdx.x;

    if (t < 72) W[t] = w[t];
    if (t >= 72 && t < 80) B[t - 72] = b[t - 72];
    if (t < 81) A[0][t] = (t / 9 == t % 9) ? 1.0f : 0.0f;
    if (t < 9)  C[0][t] = 0.0f;
    __syncthreads();

    int cur = 0;
    for (int d = 0; d < 8; ++d) {
        if (t < 81) {
            const int i = t / 9, j = t % 9;
            const int r = i / 3, cc = i % 3;
            float acc = 0.0f;
            float accc = (j == 0) ? B[d] : 0.0f;
            #pragma unroll
            for (int k = 0; k < 9; ++k) {
                const int rr = k / 3, kc = k % 3;
                const int dr = rr - r + 1, dc = kc - cc + 1;
                float m = 0.0f;
                if (dr >= 0 && dr < 3 && dc >= 0 && dc < 3)
                    m = W[d * 9 + dr * 3 + dc];
                acc = fmaf(m, A[cur][k * 9 + j], acc);
                if (j == 0) accc = fmaf(m, C[cur][k], accc);
            }
            A[1 - cur][t] = acc;
            if (j == 0) C[1 - cur][i] = accc;
        }
        __syncthreads();
        cur = 1 - cur;
    }
    if (t < 81) aff[t] = A[cur][t];
    if (t < 9)  aff[81 + t] = C[cur][t];
}

// ---------------- Kernel 2: wave-autonomous affine apply (nt streams) -------
// Tile: 256 rows = 576 v4f. Lane L loads v4f (L + 64j), j=0..8; computes rows
// L+64*jr; row read (9*row+j): 9 coprime 32 banks -> conflict-free/32 lanes.
__global__ __launch_bounds__(64) void apply_affine(
    const v4f* __restrict__ in4,
    const float* __restrict__ aff,
    v4f* __restrict__ out4,
    long long n_f4)
{
    __shared__ float tile[2304];   // 9216 B
    v4f* __restrict__ t4 = (v4f*)tile;
    const int L = threadIdx.x;
    const long long base = (long long)blockIdx.x * 576;

    // ---- stage in: 9 coalesced nt float4 loads, all in flight together ----
    v4f r[9];
    if (base + 576 <= n_f4) {
        #pragma unroll
        for (int j = 0; j < 9; ++j)
            r[j] = __builtin_nontemporal_load(in4 + base + L + (long long)j * 64);
    } else {
        #pragma unroll
        for (int j = 0; j < 9; ++j) {
            const long long g = base + L + (long long)j * 64;
            r[j] = (g < n_f4) ? __builtin_nontemporal_load(in4 + g) : (v4f)0.0f;
        }
    }
    #pragma unroll
    for (int j = 0; j < 9; ++j) t4[L + j * 64] = r[j];
    __syncthreads();   // single-wave wg: s_barrier is a HW no-op, just waitcnt

    // ---- compute 4 rows per lane, in place ----
    #pragma unroll
    for (int jr = 0; jr < 4; ++jr) {
        const int row = L + jr * 64;
        float xv[9];
        #pragma unroll
        for (int j = 0; j < 9; ++j) xv[j] = tile[row * 9 + j];
        float y[9];
        #pragma unroll
        for (int i = 0; i < 9; ++i) y[i] = aff[81 + i];
        #pragma unroll
        for (int k = 0; k < 9; ++k) {
            #pragma unroll
            for (int i = 0; i < 9; ++i)
                y[i] = fmaf(aff[i * 9 + k], xv[k], y[i]);   // aff -> SGPR (uniform)
        }
        #pragma unroll
        for (int j = 0; j < 9; ++j) tile[row * 9 + j] = y[j];
    }
    __syncthreads();

    // ---- stage out: 9 coalesced nt float4 stores ----
    #pragma unroll
    for (int j = 0; j < 9; ++j) r[j] = t4[L + j * 64];
    if (base + 576 <= n_f4) {
        #pragma unroll
        for (int j = 0; j < 9; ++j)
            __builtin_nontemporal_store(r[j], out4 + base + L + (long long)j * 64);
    } else {
        #pragma unroll
        for (int j = 0; j < 9; ++j) {
            const long long g = base + L + (long long)j * 64;
            if (g < n_f4) __builtin_nontemporal_store(r[j], out4 + g);
        }
    }
}

extern "C" void kernel_launch(void* const* d_in, const int* in_sizes, int n_in,
                              void* d_out, int out_size, void* d_ws, size_t ws_size,
                              hipStream_t stream) {
    const float* x = (const float*)d_in[0];   // [N,9] fp32
    const float* w = (const float*)d_in[1];   // [8,1,1,3,3] fp32
    const float* b = (const float*)d_in[2];   // [8] fp32
    float* out = (float*)d_out;
    float* aff = (float*)d_ws;                // 90 floats

    const long long n_elems = (long long)in_sizes[0];   // 36,000,000
    const long long n_f4    = n_elems / 4;              // 9,000,000
    const long long tiles   = (n_f4 + 575) / 576;       // 15,625 (exact)

    compose_affine<<<1, 128, 0, stream>>>(w, b, aff);
    apply_affine<<<dim3((unsigned)tiles), dim3(64), 0, stream>>>(
        (const v4f*)x, aff, (v4f*)out, n_f4);
}